// Round 1
// baseline (3695.829 us; speedup 1.0000x reference)
//
#include <hip/hip_runtime.h>

#define EDIM 1024
#define NHEADS 16
#define HDIM 64
#define TSEQ 1024
#define NBATCH 2
#define MROWS 2048
#define FFDIM 4096
#define NLAYERS 8
#define VOCAB 32000

typedef __attribute__((ext_vector_type(4))) float f32x4;
typedef __attribute__((ext_vector_type(8))) short short8;

__device__ __forceinline__ unsigned short f2bf(float f) {
    union { float f; unsigned u; } v; v.f = f;
    unsigned r = v.u + 0x7fffu + ((v.u >> 16) & 1u);
    return (unsigned short)(r >> 16);
}

__device__ __forceinline__ f32x4 mfma_bf16(short8 a, short8 b, f32x4 c) {
    return __builtin_amdgcn_mfma_f32_16x16x32_bf16(a, b, c, 0, 0, 0);
}

// ---------------- embedding: x[row] = tok_emb[idx[row]] + pos_emb[row % T] ----------
__global__ __launch_bounds__(256) void embed_kernel(
    const int* __restrict__ idx, const float* __restrict__ tok,
    const float* __restrict__ pos, float* __restrict__ x)
{
    int row = blockIdx.x;
    int t = row & (TSEQ - 1);
    int tokid = idx[row];
    const float* tp = tok + (size_t)tokid * EDIM;
    const float* pp = pos + (size_t)t * EDIM;
    float* xp = x + (size_t)row * EDIM;
    int c = threadIdx.x * 4;
    f32x4 a = *(const f32x4*)(tp + c);
    f32x4 b = *(const f32x4*)(pp + c);
    *(f32x4*)(xp + c) = a + b;
}

// ---------------- layernorm: h(bf16) = (x-mu)*rsqrt(var+eps)*s + b ------------------
__global__ __launch_bounds__(256) void ln_kernel(
    const float* __restrict__ x, const float* __restrict__ sc,
    const float* __restrict__ bi, unsigned short* __restrict__ h)
{
    int row = blockIdx.x;
    int tid = threadIdx.x;
    const float* xr = x + (size_t)row * EDIM;
    f32x4 v = *(const f32x4*)(xr + tid * 4);
    float sum = v[0] + v[1] + v[2] + v[3];
    float sq = v[0]*v[0] + v[1]*v[1] + v[2]*v[2] + v[3]*v[3];
    #pragma unroll
    for (int m = 1; m <= 32; m <<= 1) { sum += __shfl_xor(sum, m); sq += __shfl_xor(sq, m); }
    __shared__ float sh[8];
    int w = tid >> 6;
    if ((tid & 63) == 0) { sh[w] = sum; sh[4 + w] = sq; }
    __syncthreads();
    sum = sh[0] + sh[1] + sh[2] + sh[3];
    sq  = sh[4] + sh[5] + sh[6] + sh[7];
    float mu = sum * (1.0f / EDIM);
    float inv = rsqrtf(sq * (1.0f / EDIM) - mu * mu + 1e-5f);
    int c = tid * 4;
    unsigned o0 = (unsigned)f2bf((v[0] - mu) * inv * sc[c + 0] + bi[c + 0])
                | ((unsigned)f2bf((v[1] - mu) * inv * sc[c + 1] + bi[c + 1]) << 16);
    unsigned o1 = (unsigned)f2bf((v[2] - mu) * inv * sc[c + 2] + bi[c + 2])
                | ((unsigned)f2bf((v[3] - mu) * inv * sc[c + 3] + bi[c + 3]) << 16);
    unsigned* hp = (unsigned*)(h + (size_t)row * EDIM + c);
    hp[0] = o0; hp[1] = o1;
}

// ---------------- GEMM: C[M,N] = A(bf16)[M,K] @ W(f32->bf16)[K,N] + epilogue --------
// EPI 0: -> bf16      EPI 1: +bias +res -> f32      EPI 2: +bias, gelu -> bf16
// EPI 3: +bias -> f32
template<int EPI>
__global__ __launch_bounds__(256) void gemm_kernel(
    const unsigned short* __restrict__ A, const float* __restrict__ W,
    const float* __restrict__ bias, const float* __restrict__ res,
    void* __restrict__ Cout, int Ndim, int Kdim)
{
    __shared__ __align__(16) unsigned short A_lds[128][40];
    __shared__ __align__(16) unsigned short WT_lds[128][40];
    int tid = threadIdx.x;
    int bn0 = blockIdx.x * 128, bm0 = blockIdx.y * 128;
    int lane = tid & 63, w = tid >> 6;
    int wr = w >> 1, wc = w & 1;
    int r16 = lane & 15, cc = lane >> 4;

    f32x4 acc[4][4];
    #pragma unroll
    for (int m = 0; m < 4; ++m)
        #pragma unroll
        for (int n = 0; n < 4; ++n) acc[m][n] = {0.f, 0.f, 0.f, 0.f};

    int arow = tid >> 1, ahalf = tid & 1;
    const unsigned short* aptr = A + (size_t)(bm0 + arow) * Kdim + ahalf * 16;
    int wn = tid & 127, wkb = (tid >> 7) * 16;
    const float* wptr = W + (size_t)bn0 + wn;

    for (int k0 = 0; k0 < Kdim; k0 += 32) {
        // stage A tile [128][32] bf16 (row-major, padded)
        short8 a0 = *(const short8*)(aptr + k0);
        short8 a1 = *(const short8*)(aptr + k0 + 8);
        *(short8*)&A_lds[arow][ahalf * 16]     = a0;
        *(short8*)&A_lds[arow][ahalf * 16 + 8] = a1;
        // stage W tile transposed [128 n][32 k], f32->bf16, packed pairs
        #pragma unroll
        for (int i = 0; i < 8; ++i) {
            float w0 = wptr[(size_t)(k0 + wkb + 2 * i) * Ndim];
            float w1 = wptr[(size_t)(k0 + wkb + 2 * i + 1) * Ndim];
            unsigned pk = (unsigned)f2bf(w0) | ((unsigned)f2bf(w1) << 16);
            *(unsigned*)&WT_lds[wn][wkb + 2 * i] = pk;
        }
        __syncthreads();
        short8 af[4], bfr[4];
        #pragma unroll
        for (int m = 0; m < 4; ++m) af[m]  = *(const short8*)&A_lds[wr * 64 + m * 16 + r16][cc * 8];
        #pragma unroll
        for (int n = 0; n < 4; ++n) bfr[n] = *(const short8*)&WT_lds[wc * 64 + n * 16 + r16][cc * 8];
        #pragma unroll
        for (int m = 0; m < 4; ++m)
            #pragma unroll
            for (int n = 0; n < 4; ++n)
                acc[m][n] = mfma_bf16(af[m], bfr[n], acc[m][n]);
        __syncthreads();
    }

    #pragma unroll
    for (int m = 0; m < 4; ++m) {
        #pragma unroll
        for (int n = 0; n < 4; ++n) {
            #pragma unroll
            for (int j = 0; j < 4; ++j) {
                int row = bm0 + wr * 64 + m * 16 + cc * 4 + j;
                int col = bn0 + wc * 64 + n * 16 + r16;
                float vv = acc[m][n][j];
                if constexpr (EPI != 0) vv += bias[col];
                if constexpr (EPI == 1) vv += res[(size_t)row * Ndim + col];
                if constexpr (EPI == 2) vv = 0.5f * vv * (1.0f + erff(vv * 0.70710678118654752f));
                if constexpr (EPI == 0 || EPI == 2)
                    ((unsigned short*)Cout)[(size_t)row * Ndim + col] = f2bf(vv);
                else
                    ((float*)Cout)[(size_t)row * Ndim + col] = vv;
            }
        }
    }
}

// ---------------- flash attention: per (qtile=64, head, batch) ----------------------
__global__ __launch_bounds__(256) void attn_kernel(
    const unsigned short* __restrict__ q, const unsigned short* __restrict__ k,
    const unsigned short* __restrict__ v, unsigned short* __restrict__ o)
{
    __shared__ __align__(16) unsigned short K_lds[64][72];
    __shared__ __align__(16) unsigned short VT_lds[64][72];
    __shared__ __align__(16) unsigned short P_lds[4][16][72];

    int qt = blockIdx.x, head = blockIdx.y, bb = blockIdx.z;
    int tid = threadIdx.x, w = tid >> 6, lane = tid & 63;
    int r16 = lane & 15, cc = lane >> 4;
    size_t base = ((size_t)bb * TSEQ) * EDIM + head * HDIM;
    int qbase = qt * 64;

    // Q fragments (A-operand): row = lane%16 within wave's 16-row strip
    const unsigned short* qp = q + base + (size_t)(qbase + w * 16 + r16) * EDIM;
    short8 aq0 = *(const short8*)(qp + cc * 8);
    short8 aq1 = *(const short8*)(qp + 32 + cc * 8);

    f32x4 oacc[4];
    float mrow[4], lrow[4];
    #pragma unroll
    for (int n = 0; n < 4; ++n) oacc[n] = {0.f, 0.f, 0.f, 0.f};
    #pragma unroll
    for (int j = 0; j < 4; ++j) { mrow[j] = -1e30f; lrow[j] = 0.f; }

    int krow = tid >> 2, kch = tid & 3;
    int vkey = tid & 63, vdh = tid >> 6;

    for (int kt = 0; kt <= qt; ++kt) {
        int kbase = kt * 64;
        // stage K [64 keys][64 d] row-major
        const unsigned short* kp = k + base + (size_t)(kbase + krow) * EDIM + kch * 16;
        short8 kv0 = *(const short8*)kp;
        short8 kv1 = *(const short8*)(kp + 8);
        *(short8*)&K_lds[krow][kch * 16]     = kv0;
        *(short8*)&K_lds[krow][kch * 16 + 8] = kv1;
        // stage V transposed [64 d][64 keys]
        const unsigned short* vp = v + base + (size_t)(kbase + vkey) * EDIM + vdh * 16;
        short8 v0 = *(const short8*)vp;
        short8 v1 = *(const short8*)(vp + 8);
        #pragma unroll
        for (int i = 0; i < 8; ++i) {
            VT_lds[vdh * 16 + i][vkey]     = (unsigned short)v0[i];
            VT_lds[vdh * 16 + 8 + i][vkey] = (unsigned short)v1[i];
        }
        __syncthreads();

        // S = Q K^T  (per wave: 16 q-rows x 64 keys)
        f32x4 s[4];
        #pragma unroll
        for (int n = 0; n < 4; ++n) {
            short8 bk0 = *(const short8*)&K_lds[n * 16 + r16][cc * 8];
            short8 bk1 = *(const short8*)&K_lds[n * 16 + r16][32 + cc * 8];
            f32x4 z = {0.f, 0.f, 0.f, 0.f};
            z = mfma_bf16(aq0, bk0, z);
            z = mfma_bf16(aq1, bk1, z);
            s[n] = z;
        }
        bool diag = (kt == qt);
        float p[4][4];
        #pragma unroll
        for (int n = 0; n < 4; ++n)
            #pragma unroll
            for (int j = 0; j < 4; ++j) {
                float sv = s[n][j] * 0.125f;
                if (diag && (kbase + n * 16 + r16 > qbase + w * 16 + cc * 4 + j)) sv = -1e30f;
                p[n][j] = sv;
            }
        float alpha[4];
        #pragma unroll
        for (int j = 0; j < 4; ++j) {
            float tmax = fmaxf(fmaxf(p[0][j], p[1][j]), fmaxf(p[2][j], p[3][j]));
            #pragma unroll
            for (int mm = 1; mm <= 8; mm <<= 1) tmax = fmaxf(tmax, __shfl_xor(tmax, mm));
            float mnew = fmaxf(mrow[j], tmax);
            alpha[j] = __expf(mrow[j] - mnew);
            mrow[j] = mnew;
            float tsum = 0.f;
            #pragma unroll
            for (int n = 0; n < 4; ++n) {
                float pe = __expf(p[n][j] - mnew);
                p[n][j] = pe;
                tsum += pe;
            }
            #pragma unroll
            for (int mm = 1; mm <= 8; mm <<= 1) tsum += __shfl_xor(tsum, mm);
            lrow[j] = lrow[j] * alpha[j] + tsum;
        }
        // P -> bf16 via per-wave LDS (D-layout -> A-layout), rescale O
        #pragma unroll
        for (int n = 0; n < 4; ++n) {
            #pragma unroll
            for (int j = 0; j < 4; ++j) {
                P_lds[w][cc * 4 + j][n * 16 + r16] = f2bf(p[n][j]);
                oacc[n][j] *= alpha[j];
            }
        }
        short8 pa0 = *(const short8*)&P_lds[w][r16][cc * 8];
        short8 pa1 = *(const short8*)&P_lds[w][r16][32 + cc * 8];
        #pragma unroll
        for (int n = 0; n < 4; ++n) {
            short8 bv0 = *(const short8*)&VT_lds[n * 16 + r16][cc * 8];
            short8 bv1 = *(const short8*)&VT_lds[n * 16 + r16][32 + cc * 8];
            oacc[n] = mfma_bf16(pa0, bv0, oacc[n]);
            oacc[n] = mfma_bf16(pa1, bv1, oacc[n]);
        }
        __syncthreads();
    }
    #pragma unroll
    for (int n = 0; n < 4; ++n)
        #pragma unroll
        for (int j = 0; j < 4; ++j) {
            int row = qbase + w * 16 + cc * 4 + j;
            float ov = oacc[n][j] / lrow[j];
            o[base + (size_t)row * EDIM + n * 16 + r16] = f2bf(ov);
        }
}

extern "C" void kernel_launch(void* const* d_in, const int* in_sizes, int n_in,
                              void* d_out, int out_size, void* d_ws, size_t ws_size,
                              hipStream_t stream) {
    const int*   idx     = (const int*)d_in[0];
    const float* tok_emb = (const float*)d_in[1];
    const float* pos_emb = (const float*)d_in[2];
    const float* Wq      = (const float*)d_in[3];
    const float* Wk      = (const float*)d_in[4];
    const float* Wv      = (const float*)d_in[5];
    const float* Wo      = (const float*)d_in[6];
    const float* bo      = (const float*)d_in[7];
    const float* ln1_s   = (const float*)d_in[8];
    const float* ln1_b   = (const float*)d_in[9];
    const float* W1      = (const float*)d_in[10];
    const float* b1      = (const float*)d_in[11];
    const float* W2      = (const float*)d_in[12];
    const float* b2      = (const float*)d_in[13];
    const float* ln2_s   = (const float*)d_in[14];
    const float* ln2_b   = (const float*)d_in[15];
    const float* lnf_s   = (const float*)d_in[16];
    const float* lnf_b   = (const float*)d_in[17];
    const float* lm_w    = (const float*)d_in[18];
    const float* lm_b    = (const float*)d_in[19];
    float* out = (float*)d_out;

    char* ws = (char*)d_ws;
    float*          x  = (float*)ws;                                   // 8 MB
    unsigned short* h  = (unsigned short*)(ws + (8  << 20));           // 4 MB
    unsigned short* qb = (unsigned short*)(ws + (12 << 20));           // 4 MB
    unsigned short* kb = (unsigned short*)(ws + (16 << 20));           // 4 MB
    unsigned short* vb = (unsigned short*)(ws + (20 << 20));           // 4 MB
    unsigned short* ao = (unsigned short*)(ws + (24 << 20));           // 4 MB
    unsigned short* ff = (unsigned short*)(ws + (28 << 20));           // 16 MB

    dim3 blk(256);
    embed_kernel<<<MROWS, blk, 0, stream>>>(idx, tok_emb, pos_emb, x);

    for (int l = 0; l < NLAYERS; ++l) {
        ln_kernel<<<MROWS, blk, 0, stream>>>(x, ln1_s + l * EDIM, ln1_b + l * EDIM, h);
        gemm_kernel<0><<<dim3(8, 16), blk, 0, stream>>>(h, Wq + (size_t)l * EDIM * EDIM, nullptr, nullptr, qb, EDIM, EDIM);
        gemm_kernel<0><<<dim3(8, 16), blk, 0, stream>>>(h, Wk + (size_t)l * EDIM * EDIM, nullptr, nullptr, kb, EDIM, EDIM);
        gemm_kernel<0><<<dim3(8, 16), blk, 0, stream>>>(h, Wv + (size_t)l * EDIM * EDIM, nullptr, nullptr, vb, EDIM, EDIM);
        attn_kernel<<<dim3(TSEQ / 64, NHEADS, NBATCH), blk, 0, stream>>>(qb, kb, vb, ao);
        gemm_kernel<1><<<dim3(8, 16), blk, 0, stream>>>(ao, Wo + (size_t)l * EDIM * EDIM, bo + l * EDIM, x, x, EDIM, EDIM);
        ln_kernel<<<MROWS, blk, 0, stream>>>(x, ln2_s + l * EDIM, ln2_b + l * EDIM, h);
        gemm_kernel<2><<<dim3(32, 16), blk, 0, stream>>>(h, W1 + (size_t)l * EDIM * FFDIM, b1 + l * FFDIM, nullptr, ff, FFDIM, EDIM);
        gemm_kernel<1><<<dim3(8, 16), blk, 0, stream>>>(ff, W2 + (size_t)l * FFDIM * EDIM, b2 + l * EDIM, x, x, EDIM, FFDIM);
    }
    ln_kernel<<<MROWS, blk, 0, stream>>>(x, lnf_s, lnf_b, h);
    gemm_kernel<3><<<dim3(VOCAB / 128, 16), blk, 0, stream>>>(h, lm_w, lm_b, nullptr, out, VOCAB, EDIM);
}

// Round 2
// 2776.329 us; speedup vs baseline: 1.3312x; 1.3312x over previous
//
#include <hip/hip_runtime.h>

#define EDIM 1024
#define NHEADS 16
#define HDIM 64
#define TSEQ 1024
#define NBATCH 2
#define MROWS 2048
#define FFDIM 4096
#define NLAYERS 8
#define VOCAB 32000
#define QKVN 3072

typedef __attribute__((ext_vector_type(4))) float f32x4;
typedef __attribute__((ext_vector_type(8))) short short8;

__device__ __forceinline__ unsigned short f2bf(float f) {
    union { float f; unsigned u; } v; v.f = f;
    unsigned r = v.u + 0x7fffu + ((v.u >> 16) & 1u);
    return (unsigned short)(r >> 16);
}

__device__ __forceinline__ f32x4 mfma_bf16(short8 a, short8 b, f32x4 c) {
    return __builtin_amdgcn_mfma_f32_16x16x32_bf16(a, b, c, 0, 0, 0);
}

// ---------------- embedding ----------------
__global__ __launch_bounds__(256) void embed_kernel(
    const int* __restrict__ idx, const float* __restrict__ tok,
    const float* __restrict__ pos, float* __restrict__ x)
{
    int row = blockIdx.x;
    int t = row & (TSEQ - 1);
    int tokid = idx[row];
    const float* tp = tok + (size_t)tokid * EDIM;
    const float* pp = pos + (size_t)t * EDIM;
    float* xp = x + (size_t)row * EDIM;
    int c = threadIdx.x * 4;
    f32x4 a = *(const f32x4*)(tp + c);
    f32x4 b = *(const f32x4*)(pp + c);
    *(f32x4*)(xp + c) = a + b;
}

// ---------------- layernorm -> bf16 ----------------
__global__ __launch_bounds__(256) void ln_kernel(
    const float* __restrict__ x, const float* __restrict__ sc,
    const float* __restrict__ bi, unsigned short* __restrict__ h)
{
    int row = blockIdx.x;
    int tid = threadIdx.x;
    const float* xr = x + (size_t)row * EDIM;
    f32x4 v = *(const f32x4*)(xr + tid * 4);
    float sum = v[0] + v[1] + v[2] + v[3];
    float sq = v[0]*v[0] + v[1]*v[1] + v[2]*v[2] + v[3]*v[3];
    #pragma unroll
    for (int m = 1; m <= 32; m <<= 1) { sum += __shfl_xor(sum, m); sq += __shfl_xor(sq, m); }
    __shared__ float sh[8];
    int w = tid >> 6;
    if ((tid & 63) == 0) { sh[w] = sum; sh[4 + w] = sq; }
    __syncthreads();
    sum = sh[0] + sh[1] + sh[2] + sh[3];
    sq  = sh[4] + sh[5] + sh[6] + sh[7];
    float mu = sum * (1.0f / EDIM);
    float inv = rsqrtf(sq * (1.0f / EDIM) - mu * mu + 1e-5f);
    int c = tid * 4;
    unsigned o0 = (unsigned)f2bf((v[0] - mu) * inv * sc[c + 0] + bi[c + 0])
                | ((unsigned)f2bf((v[1] - mu) * inv * sc[c + 1] + bi[c + 1]) << 16);
    unsigned o1 = (unsigned)f2bf((v[2] - mu) * inv * sc[c + 2] + bi[c + 2])
                | ((unsigned)f2bf((v[3] - mu) * inv * sc[c + 3] + bi[c + 3]) << 16);
    unsigned* hp = (unsigned*)(h + (size_t)row * EDIM + c);
    hp[0] = o0; hp[1] = o1;
}

// ---------------- weight convert+transpose: W[K,N] f32 -> WT[N,K] bf16 -------------
__global__ __launch_bounds__(256) void wconv_kernel(
    const float* __restrict__ W, unsigned short* __restrict__ WT, int Kdim, int Ndim)
{
    __shared__ unsigned short T[64][72];
    int k0 = blockIdx.x * 64, n0 = blockIdx.y * 64;
    int t = threadIdx.x;
    int r = t >> 4, c4 = (t & 15) * 4;
    #pragma unroll
    for (int i = 0; i < 4; ++i) {
        f32x4 v = *(const f32x4*)(W + (size_t)(k0 + r + 16 * i) * Ndim + n0 + c4);
        T[c4 + 0][r + 16 * i] = f2bf(v[0]);
        T[c4 + 1][r + 16 * i] = f2bf(v[1]);
        T[c4 + 2][r + 16 * i] = f2bf(v[2]);
        T[c4 + 3][r + 16 * i] = f2bf(v[3]);
    }
    __syncthreads();
    int nr = t >> 2, kc = (t & 3) * 16;
    short8 o0 = *(const short8*)&T[nr][kc];
    short8 o1 = *(const short8*)&T[nr][kc + 8];
    *(short8*)(WT + (size_t)(n0 + nr) * Kdim + k0 + kc)     = o0;
    *(short8*)(WT + (size_t)(n0 + nr) * Kdim + k0 + kc + 8) = o1;
}

// ---------------- GEMM: C[M,N] = A(bf16)[M,K] @ WT(bf16)[N,K]^T + epilogue ---------
// BN=128, BK=64. EPI 0: ->bf16  1: +bias+res->f32  2: +bias,gelu->bf16  3: +bias->f32
template<int BM, int EPI>
__global__ __launch_bounds__(256, 2) void gemm_kernel(
    const unsigned short* __restrict__ A, const unsigned short* __restrict__ WT,
    const float* __restrict__ bias, const float* __restrict__ res,
    void* __restrict__ Cout, int Ndim, int Kdim, int ntiles, int nwg)
{
    constexpr int MF = BM / 32;            // m-fragments per wave
    __shared__ __align__(16) unsigned short A_lds[BM][72];
    __shared__ __align__(16) unsigned short B_lds[128][72];
    int tid = threadIdx.x;
    // bijective XCD swizzle (nwg % 8 == 0), m-major decomposition
    int q8 = nwg >> 3;
    int swz = (blockIdx.x & 7) * q8 + (blockIdx.x >> 3);
    int bm0 = (swz / ntiles) * BM, bn0 = (swz % ntiles) * 128;
    int lane = tid & 63, w = tid >> 6;
    int wr = w >> 1, wc = w & 1;
    int r16 = lane & 15, cc = lane >> 4;

    f32x4 acc[MF][4];
    #pragma unroll
    for (int m = 0; m < MF; ++m)
        #pragma unroll
        for (int n = 0; n < 4; ++n) acc[m][n] = {0.f, 0.f, 0.f, 0.f};

    for (int k0 = 0; k0 < Kdim; k0 += 64) {
        // stage A tile [BM][64] bf16 : grid of short8 [BM][8]
        #pragma unroll
        for (int i = 0; i < BM / 32; ++i) {
            int idx = tid + 256 * i;
            int row = idx >> 3, c8 = (idx & 7) * 8;
            short8 va = *(const short8*)(A + (size_t)(bm0 + row) * Kdim + k0 + c8);
            *(short8*)&A_lds[row][c8] = va;
        }
        // stage B tile [128][64] from WT rows (K-contiguous)
        #pragma unroll
        for (int i = 0; i < 4; ++i) {
            int idx = tid + 256 * i;
            int row = idx >> 3, c8 = (idx & 7) * 8;
            short8 vb = *(const short8*)(WT + (size_t)(bn0 + row) * Kdim + k0 + c8);
            *(short8*)&B_lds[row][c8] = vb;
        }
        __syncthreads();
        #pragma unroll
        for (int kh = 0; kh < 2; ++kh) {
            short8 af[MF], bfr[4];
            #pragma unroll
            for (int m = 0; m < MF; ++m)
                af[m] = *(const short8*)&A_lds[wr * (BM / 2) + m * 16 + r16][kh * 32 + cc * 8];
            #pragma unroll
            for (int n = 0; n < 4; ++n)
                bfr[n] = *(const short8*)&B_lds[wc * 64 + n * 16 + r16][kh * 32 + cc * 8];
            #pragma unroll
            for (int m = 0; m < MF; ++m)
                #pragma unroll
                for (int n = 0; n < 4; ++n)
                    acc[m][n] = mfma_bf16(af[m], bfr[n], acc[m][n]);
        }
        __syncthreads();
    }

    #pragma unroll
    for (int m = 0; m < MF; ++m) {
        #pragma unroll
        for (int n = 0; n < 4; ++n) {
            #pragma unroll
            for (int j = 0; j < 4; ++j) {
                int row = bm0 + wr * (BM / 2) + m * 16 + cc * 4 + j;
                int col = bn0 + wc * 64 + n * 16 + r16;
                float vv = acc[m][n][j];
                if constexpr (EPI != 0) vv += bias[col];
                if constexpr (EPI == 1) vv += res[(size_t)row * Ndim + col];
                if constexpr (EPI == 2) vv = 0.5f * vv * (1.0f + erff(vv * 0.70710678118654752f));
                if constexpr (EPI == 0 || EPI == 2)
                    ((unsigned short*)Cout)[(size_t)row * Ndim + col] = f2bf(vv);
                else
                    ((float*)Cout)[(size_t)row * Ndim + col] = vv;
            }
        }
    }
}

// ---------------- flash attention (q,k,v from fused qkv buffer, stride QKVN) -------
__global__ __launch_bounds__(256) void attn_kernel(
    const unsigned short* __restrict__ qkv, unsigned short* __restrict__ o)
{
    __shared__ __align__(16) unsigned short K_lds[64][72];
    __shared__ __align__(16) unsigned short VT_lds[64][72];
    __shared__ __align__(16) unsigned short P_lds[4][16][72];

    int qt = blockIdx.x, head = blockIdx.y, bb = blockIdx.z;
    int tid = threadIdx.x, w = tid >> 6, lane = tid & 63;
    int r16 = lane & 15, cc = lane >> 4;
    size_t base = ((size_t)bb * TSEQ) * QKVN + head * HDIM;
    const unsigned short* q = qkv + base;
    const unsigned short* k = qkv + base + EDIM;
    const unsigned short* v = qkv + base + 2 * EDIM;
    size_t obase = ((size_t)bb * TSEQ) * EDIM + head * HDIM;
    int qbase = qt * 64;

    const unsigned short* qp = q + (size_t)(qbase + w * 16 + r16) * QKVN;
    short8 aq0 = *(const short8*)(qp + cc * 8);
    short8 aq1 = *(const short8*)(qp + 32 + cc * 8);

    f32x4 oacc[4];
    float mrow[4], lrow[4];
    #pragma unroll
    for (int n = 0; n < 4; ++n) oacc[n] = {0.f, 0.f, 0.f, 0.f};
    #pragma unroll
    for (int j = 0; j < 4; ++j) { mrow[j] = -1e30f; lrow[j] = 0.f; }

    int krow = tid >> 2, kch = tid & 3;
    int vkey = tid & 63, vdh = tid >> 6;

    for (int kt = 0; kt <= qt; ++kt) {
        int kbase = kt * 64;
        const unsigned short* kp = k + (size_t)(kbase + krow) * QKVN + kch * 16;
        short8 kv0 = *(const short8*)kp;
        short8 kv1 = *(const short8*)(kp + 8);
        *(short8*)&K_lds[krow][kch * 16]     = kv0;
        *(short8*)&K_lds[krow][kch * 16 + 8] = kv1;
        const unsigned short* vp = v + (size_t)(kbase + vkey) * QKVN + vdh * 16;
        short8 v0 = *(const short8*)vp;
        short8 v1 = *(const short8*)(vp + 8);
        #pragma unroll
        for (int i = 0; i < 8; ++i) {
            VT_lds[vdh * 16 + i][vkey]     = (unsigned short)v0[i];
            VT_lds[vdh * 16 + 8 + i][vkey] = (unsigned short)v1[i];
        }
        __syncthreads();

        f32x4 s[4];
        #pragma unroll
        for (int n = 0; n < 4; ++n) {
            short8 bk0 = *(const short8*)&K_lds[n * 16 + r16][cc * 8];
            short8 bk1 = *(const short8*)&K_lds[n * 16 + r16][32 + cc * 8];
            f32x4 z = {0.f, 0.f, 0.f, 0.f};
            z = mfma_bf16(aq0, bk0, z);
            z = mfma_bf16(aq1, bk1, z);
            s[n] = z;
        }
        bool diag = (kt == qt);
        float p[4][4];
        #pragma unroll
        for (int n = 0; n < 4; ++n)
            #pragma unroll
            for (int j = 0; j < 4; ++j) {
                float sv = s[n][j] * 0.125f;
                if (diag && (kbase + n * 16 + r16 > qbase + w * 16 + cc * 4 + j)) sv = -1e30f;
                p[n][j] = sv;
            }
        float alpha[4];
        #pragma unroll
        for (int j = 0; j < 4; ++j) {
            float tmax = fmaxf(fmaxf(p[0][j], p[1][j]), fmaxf(p[2][j], p[3][j]));
            #pragma unroll
            for (int mm = 1; mm <= 8; mm <<= 1) tmax = fmaxf(tmax, __shfl_xor(tmax, mm));
            float mnew = fmaxf(mrow[j], tmax);
            alpha[j] = __expf(mrow[j] - mnew);
            mrow[j] = mnew;
            float tsum = 0.f;
            #pragma unroll
            for (int n = 0; n < 4; ++n) {
                float pe = __expf(p[n][j] - mnew);
                p[n][j] = pe;
                tsum += pe;
            }
            #pragma unroll
            for (int mm = 1; mm <= 8; mm <<= 1) tsum += __shfl_xor(tsum, mm);
            lrow[j] = lrow[j] * alpha[j] + tsum;
        }
        #pragma unroll
        for (int n = 0; n < 4; ++n) {
            #pragma unroll
            for (int j = 0; j < 4; ++j) {
                P_lds[w][cc * 4 + j][n * 16 + r16] = f2bf(p[n][j]);
                oacc[n][j] *= alpha[j];
            }
        }
        short8 pa0 = *(const short8*)&P_lds[w][r16][cc * 8];
        short8 pa1 = *(const short8*)&P_lds[w][r16][32 + cc * 8];
        #pragma unroll
        for (int n = 0; n < 4; ++n) {
            short8 bv0 = *(const short8*)&VT_lds[n * 16 + r16][cc * 8];
            short8 bv1 = *(const short8*)&VT_lds[n * 16 + r16][32 + cc * 8];
            oacc[n] = mfma_bf16(pa0, bv0, oacc[n]);
            oacc[n] = mfma_bf16(pa1, bv1, oacc[n]);
        }
        __syncthreads();
    }
    #pragma unroll
    for (int n = 0; n < 4; ++n)
        #pragma unroll
        for (int j = 0; j < 4; ++j) {
            int row = qbase + w * 16 + cc * 4 + j;
            float ov = oacc[n][j] / lrow[j];
            o[obase + (size_t)row * EDIM + n * 16 + r16] = f2bf(ov);
        }
}

extern "C" void kernel_launch(void* const* d_in, const int* in_sizes, int n_in,
                              void* d_out, int out_size, void* d_ws, size_t ws_size,
                              hipStream_t stream) {
    const int*   idx     = (const int*)d_in[0];
    const float* tok_emb = (const float*)d_in[1];
    const float* pos_emb = (const float*)d_in[2];
    const float* Wq      = (const float*)d_in[3];
    const float* Wk      = (const float*)d_in[4];
    const float* Wv      = (const float*)d_in[5];
    const float* Wo      = (const float*)d_in[6];
    const float* bo      = (const float*)d_in[7];
    const float* ln1_s   = (const float*)d_in[8];
    const float* ln1_b   = (const float*)d_in[9];
    const float* W1      = (const float*)d_in[10];
    const float* b1      = (const float*)d_in[11];
    const float* W2      = (const float*)d_in[12];
    const float* b2      = (const float*)d_in[13];
    const float* ln2_s   = (const float*)d_in[14];
    const float* ln2_b   = (const float*)d_in[15];
    const float* lnf_s   = (const float*)d_in[16];
    const float* lnf_b   = (const float*)d_in[17];
    const float* lm_w    = (const float*)d_in[18];
    const float* lm_b    = (const float*)d_in[19];
    float* out = (float*)d_out;

    char* ws = (char*)d_ws;
    float*          x    = (float*)ws;                                  // 8 MB
    unsigned short* h    = (unsigned short*)(ws + (8  << 20));          // 4 MB
    unsigned short* qkv  = (unsigned short*)(ws + (12 << 20));          // 12 MB
    unsigned short* ao   = (unsigned short*)(ws + (24 << 20));          // 4 MB
    unsigned short* ff   = (unsigned short*)(ws + (28 << 20));          // 16 MB
    unsigned short* qkvT = (unsigned short*)(ws + (44 << 20));          // 6 MB [3072][1024]
    unsigned short* woT  = (unsigned short*)(ws + (50 << 20));          // 2 MB [1024][1024]
    unsigned short* w1T  = (unsigned short*)(ws + (52 << 20));          // 8 MB [4096][1024]
    unsigned short* w2T  = (unsigned short*)(ws + (60 << 20));          // 8 MB [1024][4096]
    unsigned short* lmT  = (unsigned short*)(ws + (68 << 20));          // 62.5 MB [32000][1024]

    dim3 blk(256);
    embed_kernel<<<MROWS, blk, 0, stream>>>(idx, tok_emb, pos_emb, x);

    for (int l = 0; l < NLAYERS; ++l) {
        // convert this layer's weights to bf16 transposed
        wconv_kernel<<<dim3(16, 16), blk, 0, stream>>>(Wq + (size_t)l * EDIM * EDIM, qkvT, EDIM, EDIM);
        wconv_kernel<<<dim3(16, 16), blk, 0, stream>>>(Wk + (size_t)l * EDIM * EDIM, qkvT + (size_t)EDIM * EDIM, EDIM, EDIM);
        wconv_kernel<<<dim3(16, 16), blk, 0, stream>>>(Wv + (size_t)l * EDIM * EDIM, qkvT + (size_t)2 * EDIM * EDIM, EDIM, EDIM);
        wconv_kernel<<<dim3(16, 16), blk, 0, stream>>>(Wo + (size_t)l * EDIM * EDIM, woT, EDIM, EDIM);
        wconv_kernel<<<dim3(16, 64), blk, 0, stream>>>(W1 + (size_t)l * EDIM * FFDIM, w1T, EDIM, FFDIM);
        wconv_kernel<<<dim3(64, 16), blk, 0, stream>>>(W2 + (size_t)l * FFDIM * EDIM, w2T, FFDIM, EDIM);

        ln_kernel<<<MROWS, blk, 0, stream>>>(x, ln1_s + l * EDIM, ln1_b + l * EDIM, h);
        gemm_kernel<128, 0><<<24 * 16, blk, 0, stream>>>(h, qkvT, nullptr, nullptr, qkv, QKVN, EDIM, 24, 24 * 16);
        attn_kernel<<<dim3(TSEQ / 64, NHEADS, NBATCH), blk, 0, stream>>>(qkv, ao);
        gemm_kernel<64, 1><<<8 * 32, blk, 0, stream>>>(ao, woT, bo + l * EDIM, x, x, EDIM, EDIM, 8, 8 * 32);
        ln_kernel<<<MROWS, blk, 0, stream>>>(x, ln2_s + l * EDIM, ln2_b + l * EDIM, h);
        gemm_kernel<128, 2><<<32 * 16, blk, 0, stream>>>(h, w1T, b1 + l * FFDIM, nullptr, ff, FFDIM, EDIM, 32, 32 * 16);
        gemm_kernel<64, 1><<<8 * 32, blk, 0, stream>>>(ff, w2T, b2 + l * EDIM, x, x, EDIM, FFDIM, 8, 8 * 32);
    }
    ln_kernel<<<MROWS, blk, 0, stream>>>(x, lnf_s, lnf_b, h);
    wconv_kernel<<<dim3(16, 500), blk, 0, stream>>>(lm_w, lmT, EDIM, VOCAB);
    gemm_kernel<128, 3><<<250 * 16, blk, 0, stream>>>(h, lmT, lm_b, nullptr, out, VOCAB, EDIM, 250, 250 * 16);
}

// Round 3
// 1992.099 us; speedup vs baseline: 1.8552x; 1.3937x over previous
//
#include <hip/hip_runtime.h>

#define EDIM 1024
#define NHEADS 16
#define HDIM 64
#define TSEQ 1024
#define NBATCH 2
#define MROWS 2048
#define FFDIM 4096
#define NLAYERS 8
#define VOCAB 32000
#define QKVN 3072

typedef __attribute__((ext_vector_type(4))) float f32x4;
typedef __attribute__((ext_vector_type(8))) short short8;

__device__ __forceinline__ unsigned short f2bf(float f) {
    union { float f; unsigned u; } v; v.f = f;
    unsigned r = v.u + 0x7fffu + ((v.u >> 16) & 1u);
    return (unsigned short)(r >> 16);
}

__device__ __forceinline__ f32x4 mfma_bf16(short8 a, short8 b, f32x4 c) {
    return __builtin_amdgcn_mfma_f32_16x16x32_bf16(a, b, c, 0, 0, 0);
}

// async global->LDS, 16B per lane; LDS dest = wave-uniform base + lane*16
__device__ __forceinline__ void gload16(const unsigned short* g, unsigned short* l) {
    __builtin_amdgcn_global_load_lds(
        (const __attribute__((address_space(1))) unsigned int*)g,
        (__attribute__((address_space(3))) unsigned int*)l, 16, 0, 0);
}

// ---------------- embedding ----------------
__global__ __launch_bounds__(256) void embed_kernel(
    const int* __restrict__ idx, const float* __restrict__ tok,
    const float* __restrict__ pos, float* __restrict__ x)
{
    int row = blockIdx.x;
    int t = row & (TSEQ - 1);
    int tokid = idx[row];
    const float* tp = tok + (size_t)tokid * EDIM;
    const float* pp = pos + (size_t)t * EDIM;
    float* xp = x + (size_t)row * EDIM;
    int c = threadIdx.x * 4;
    f32x4 a = *(const f32x4*)(tp + c);
    f32x4 b = *(const f32x4*)(pp + c);
    *(f32x4*)(xp + c) = a + b;
}

// ---------------- layernorm -> bf16 ----------------
__global__ __launch_bounds__(256) void ln_kernel(
    const float* __restrict__ x, const float* __restrict__ sc,
    const float* __restrict__ bi, unsigned short* __restrict__ h)
{
    int row = blockIdx.x;
    int tid = threadIdx.x;
    const float* xr = x + (size_t)row * EDIM;
    f32x4 v = *(const f32x4*)(xr + tid * 4);
    float sum = v[0] + v[1] + v[2] + v[3];
    float sq = v[0]*v[0] + v[1]*v[1] + v[2]*v[2] + v[3]*v[3];
    #pragma unroll
    for (int m = 1; m <= 32; m <<= 1) { sum += __shfl_xor(sum, m); sq += __shfl_xor(sq, m); }
    __shared__ float sh[8];
    int w = tid >> 6;
    if ((tid & 63) == 0) { sh[w] = sum; sh[4 + w] = sq; }
    __syncthreads();
    sum = sh[0] + sh[1] + sh[2] + sh[3];
    sq  = sh[4] + sh[5] + sh[6] + sh[7];
    float mu = sum * (1.0f / EDIM);
    float inv = rsqrtf(sq * (1.0f / EDIM) - mu * mu + 1e-5f);
    int c = tid * 4;
    unsigned o0 = (unsigned)f2bf((v[0] - mu) * inv * sc[c + 0] + bi[c + 0])
                | ((unsigned)f2bf((v[1] - mu) * inv * sc[c + 1] + bi[c + 1]) << 16);
    unsigned o1 = (unsigned)f2bf((v[2] - mu) * inv * sc[c + 2] + bi[c + 2])
                | ((unsigned)f2bf((v[3] - mu) * inv * sc[c + 3] + bi[c + 3]) << 16);
    unsigned* hp = (unsigned*)(h + (size_t)row * EDIM + c);
    hp[0] = o0; hp[1] = o1;
}

// ---------------- weight convert+transpose tile (64x64) ----------------
__device__ __forceinline__ void conv_tile(
    const float* __restrict__ W, unsigned short* __restrict__ WT,
    int Kdim, int Ndim, int k0, int n0, int tid)
{
    __shared__ unsigned short T[64][72];
    int r = tid >> 4, c4 = (tid & 15) * 4;
    #pragma unroll
    for (int i = 0; i < 4; ++i) {
        f32x4 v = *(const f32x4*)(W + (size_t)(k0 + r + 16 * i) * Ndim + n0 + c4);
        T[c4 + 0][r + 16 * i] = f2bf(v[0]);
        T[c4 + 1][r + 16 * i] = f2bf(v[1]);
        T[c4 + 2][r + 16 * i] = f2bf(v[2]);
        T[c4 + 3][r + 16 * i] = f2bf(v[3]);
    }
    __syncthreads();
    int nr = tid >> 2, kc = (tid & 3) * 16;
    short8 o0 = *(const short8*)&T[nr][kc];
    short8 o1 = *(const short8*)&T[nr][kc + 8];
    *(short8*)(WT + (size_t)(n0 + nr) * Kdim + k0 + kc)     = o0;
    *(short8*)(WT + (size_t)(n0 + nr) * Kdim + k0 + kc + 8) = o1;
}

// all per-layer weights in one launch: 3072 blocks
__global__ __launch_bounds__(256) void wconv_layer_kernel(
    const float* __restrict__ Wq, const float* __restrict__ Wk,
    const float* __restrict__ Wv, const float* __restrict__ Wo,
    const float* __restrict__ W1, const float* __restrict__ W2,
    unsigned short* __restrict__ qkvT, unsigned short* __restrict__ woT,
    unsigned short* __restrict__ w1T, unsigned short* __restrict__ w2T)
{
    int bid = blockIdx.x, tid = threadIdx.x;
    if (bid < 768) {
        int wsel = bid >> 8, t = bid & 255;
        const float* src = wsel == 0 ? Wq : (wsel == 1 ? Wk : Wv);
        conv_tile(src, qkvT + (size_t)wsel * EDIM * EDIM, EDIM, EDIM,
                  (t & 15) * 64, (t >> 4) * 64, tid);
    } else if (bid < 1024) {
        int t = bid - 768;
        conv_tile(Wo, woT, EDIM, EDIM, (t & 15) * 64, (t >> 4) * 64, tid);
    } else if (bid < 2048) {
        int t = bid - 1024;
        conv_tile(W1, w1T, EDIM, FFDIM, (t & 15) * 64, (t >> 4) * 64, tid);
    } else {
        int t = bid - 2048;
        conv_tile(W2, w2T, FFDIM, EDIM, (t >> 4) * 64, (t & 15) * 64, tid);
    }
}

__global__ __launch_bounds__(256) void wconv_kernel(
    const float* __restrict__ W, unsigned short* __restrict__ WT, int Kdim, int Ndim)
{
    conv_tile(W, WT, Kdim, Ndim, blockIdx.x * 64, blockIdx.y * 64, threadIdx.x);
}

// ---------------- wide GEMM: block 128Mx256N, 4 waves (2Mx2N), wave 64x128, BK=64 --
// EPI 0: ->bf16   2: +bias,gelu->bf16   3: +bias->f32   4: partial f32 (split-K)
template<int EPI, int NMAJOR>
__global__ __launch_bounds__(256, 2) void gemm_wide(
    const unsigned short* __restrict__ A, const unsigned short* __restrict__ WT,
    const float* __restrict__ bias, float* __restrict__ Cf,
    unsigned short* __restrict__ Cb, int Ndim, int Kdim,
    int mtiles, int ntiles, int kspan)
{
    __shared__ __align__(16) unsigned short A_lds[128][64];
    __shared__ __align__(16) unsigned short B_lds[256][64];
    int tid = threadIdx.x;
    int nwg = mtiles * ntiles;
    int q8 = nwg >> 3;
    int swz = (int)(blockIdx.x & 7) * q8 + (int)(blockIdx.x >> 3);
    int bm0, bn0;
    if constexpr (NMAJOR) { bn0 = (swz / mtiles) * 256; bm0 = (swz % mtiles) * 128; }
    else                  { bm0 = (swz / ntiles) * 128; bn0 = (swz % ntiles) * 256; }
    int kz = blockIdx.y;
    int lane = tid & 63, w = tid >> 6;
    int wr = w >> 1, wc = w & 1;
    int r16 = lane & 15, cc = lane >> 4;
    int lrow = lane >> 3, lcol = (lane & 7) * 8;   // staging: row-in-chunk, col

    f32x4 acc[4][8];
    #pragma unroll
    for (int m = 0; m < 4; ++m)
        #pragma unroll
        for (int n = 0; n < 8; ++n) acc[m][n] = {0.f, 0.f, 0.f, 0.f};

    int kbeg = kz * kspan;
    int kend = kbeg + kspan;
    for (int k0 = kbeg; k0 < kend; k0 += 64) {
        // A tile [128][64] = 16 chunks of 1KB; chunk c -> rows c*8..c*8+7
        #pragma unroll
        for (int i = 0; i < 4; ++i) {
            int c = i * 4 + w;
            gload16(A + (size_t)(bm0 + c * 8 + lrow) * Kdim + k0 + lcol,
                    (unsigned short*)A_lds + c * 512);
        }
        // B tile [256][64] = 32 chunks
        #pragma unroll
        for (int i = 0; i < 8; ++i) {
            int c = i * 4 + w;
            gload16(WT + (size_t)(bn0 + c * 8 + lrow) * Kdim + k0 + lcol,
                    (unsigned short*)B_lds + c * 512);
        }
        __syncthreads();
        #pragma unroll
        for (int kh = 0; kh < 2; ++kh) {
            short8 af[4], bfr[8];
            #pragma unroll
            for (int m = 0; m < 4; ++m)
                af[m] = *(const short8*)&A_lds[wr * 64 + m * 16 + r16][kh * 32 + cc * 8];
            #pragma unroll
            for (int n = 0; n < 8; ++n)
                bfr[n] = *(const short8*)&B_lds[wc * 128 + n * 16 + r16][kh * 32 + cc * 8];
            #pragma unroll
            for (int m = 0; m < 4; ++m)
                #pragma unroll
                for (int n = 0; n < 8; ++n)
                    acc[m][n] = mfma_bf16(af[m], bfr[n], acc[m][n]);
        }
        __syncthreads();
    }

    float* Cpart = Cf + (size_t)kz * MROWS * Ndim;
    #pragma unroll
    for (int m = 0; m < 4; ++m) {
        #pragma unroll
        for (int n = 0; n < 8; ++n) {
            #pragma unroll
            for (int j = 0; j < 4; ++j) {
                int row = bm0 + wr * 64 + m * 16 + cc * 4 + j;
                int col = bn0 + wc * 128 + n * 16 + r16;
                float vv = acc[m][n][j];
                if constexpr (EPI == 2 || EPI == 3) vv += bias[col];
                if constexpr (EPI == 2) vv = 0.5f * vv * (1.0f + erff(vv * 0.70710678118654752f));
                if constexpr (EPI == 0 || EPI == 2)
                    Cb[(size_t)row * Ndim + col] = f2bf(vv);
                else if constexpr (EPI == 3)
                    Cf[(size_t)row * Ndim + col] = vv;
                else
                    Cpart[(size_t)row * Ndim + col] = vv;
            }
        }
    }
}

// ---------------- split-K reduce: x += bias + sum_kz part ----------------
template<int KZ>
__global__ __launch_bounds__(256) void reduce_kernel(
    const float* __restrict__ part, const float* __restrict__ bias,
    float* __restrict__ x)
{
    int row = blockIdx.x;
    int c = threadIdx.x * 4;
    f32x4 s = *(const f32x4*)(x + (size_t)row * EDIM + c);
    s += *(const f32x4*)(bias + c);
    #pragma unroll
    for (int kz = 0; kz < KZ; ++kz)
        s += *(const f32x4*)(part + ((size_t)kz * MROWS + row) * EDIM + c);
    *(f32x4*)(x + (size_t)row * EDIM + c) = s;
}

// ---------------- flash attention (q,k,v from fused qkv buffer, stride QKVN) -------
__global__ __launch_bounds__(256) void attn_kernel(
    const unsigned short* __restrict__ qkv, unsigned short* __restrict__ o)
{
    __shared__ __align__(16) unsigned short K_lds[64][72];
    __shared__ __align__(16) unsigned short VT_lds[64][72];
    __shared__ __align__(16) unsigned short P_lds[4][16][72];

    int qt = blockIdx.x, head = blockIdx.y, bb = blockIdx.z;
    int tid = threadIdx.x, w = tid >> 6, lane = tid & 63;
    int r16 = lane & 15, cc = lane >> 4;
    size_t base = ((size_t)bb * TSEQ) * QKVN + head * HDIM;
    const unsigned short* q = qkv + base;
    const unsigned short* k = qkv + base + EDIM;
    const unsigned short* v = qkv + base + 2 * EDIM;
    size_t obase = ((size_t)bb * TSEQ) * EDIM + head * HDIM;
    int qbase = qt * 64;

    const unsigned short* qp = q + (size_t)(qbase + w * 16 + r16) * QKVN;
    short8 aq0 = *(const short8*)(qp + cc * 8);
    short8 aq1 = *(const short8*)(qp + 32 + cc * 8);

    f32x4 oacc[4];
    float mrow[4], lrow[4];
    #pragma unroll
    for (int n = 0; n < 4; ++n) oacc[n] = {0.f, 0.f, 0.f, 0.f};
    #pragma unroll
    for (int j = 0; j < 4; ++j) { mrow[j] = -1e30f; lrow[j] = 0.f; }

    int krow = tid >> 2, kch = tid & 3;
    int vkey = tid & 63, vdh = tid >> 6;

    for (int kt = 0; kt <= qt; ++kt) {
        int kbase = kt * 64;
        const unsigned short* kp = k + (size_t)(kbase + krow) * QKVN + kch * 16;
        short8 kv0 = *(const short8*)kp;
        short8 kv1 = *(const short8*)(kp + 8);
        *(short8*)&K_lds[krow][kch * 16]     = kv0;
        *(short8*)&K_lds[krow][kch * 16 + 8] = kv1;
        const unsigned short* vp = v + (size_t)(kbase + vkey) * QKVN + vdh * 16;
        short8 v0 = *(const short8*)vp;
        short8 v1 = *(const short8*)(vp + 8);
        #pragma unroll
        for (int i = 0; i < 8; ++i) {
            VT_lds[vdh * 16 + i][vkey]     = (unsigned short)v0[i];
            VT_lds[vdh * 16 + 8 + i][vkey] = (unsigned short)v1[i];
        }
        __syncthreads();

        f32x4 s[4];
        #pragma unroll
        for (int n = 0; n < 4; ++n) {
            short8 bk0 = *(const short8*)&K_lds[n * 16 + r16][cc * 8];
            short8 bk1 = *(const short8*)&K_lds[n * 16 + r16][32 + cc * 8];
            f32x4 z = {0.f, 0.f, 0.f, 0.f};
            z = mfma_bf16(aq0, bk0, z);
            z = mfma_bf16(aq1, bk1, z);
            s[n] = z;
        }
        bool diag = (kt == qt);
        float p[4][4];
        #pragma unroll
        for (int n = 0; n < 4; ++n)
            #pragma unroll
            for (int j = 0; j < 4; ++j) {
                float sv = s[n][j] * 0.125f;
                if (diag && (kbase + n * 16 + r16 > qbase + w * 16 + cc * 4 + j)) sv = -1e30f;
                p[n][j] = sv;
            }
        float alpha[4];
        #pragma unroll
        for (int j = 0; j < 4; ++j) {
            float tmax = fmaxf(fmaxf(p[0][j], p[1][j]), fmaxf(p[2][j], p[3][j]));
            #pragma unroll
            for (int mm = 1; mm <= 8; mm <<= 1) tmax = fmaxf(tmax, __shfl_xor(tmax, mm));
            float mnew = fmaxf(mrow[j], tmax);
            alpha[j] = __expf(mrow[j] - mnew);
            mrow[j] = mnew;
            float tsum = 0.f;
            #pragma unroll
            for (int n = 0; n < 4; ++n) {
                float pe = __expf(p[n][j] - mnew);
                p[n][j] = pe;
                tsum += pe;
            }
            #pragma unroll
            for (int mm = 1; mm <= 8; mm <<= 1) tsum += __shfl_xor(tsum, mm);
            lrow[j] = lrow[j] * alpha[j] + tsum;
        }
        #pragma unroll
        for (int n = 0; n < 4; ++n) {
            #pragma unroll
            for (int j = 0; j < 4; ++j) {
                P_lds[w][cc * 4 + j][n * 16 + r16] = f2bf(p[n][j]);
                oacc[n][j] *= alpha[j];
            }
        }
        short8 pa0 = *(const short8*)&P_lds[w][r16][cc * 8];
        short8 pa1 = *(const short8*)&P_lds[w][r16][32 + cc * 8];
        #pragma unroll
        for (int n = 0; n < 4; ++n) {
            short8 bv0 = *(const short8*)&VT_lds[n * 16 + r16][cc * 8];
            short8 bv1 = *(const short8*)&VT_lds[n * 16 + r16][32 + cc * 8];
            oacc[n] = mfma_bf16(pa0, bv0, oacc[n]);
            oacc[n] = mfma_bf16(pa1, bv1, oacc[n]);
        }
        __syncthreads();
    }
    #pragma unroll
    for (int n = 0; n < 4; ++n)
        #pragma unroll
        for (int j = 0; j < 4; ++j) {
            int row = qbase + w * 16 + cc * 4 + j;
            float ov = oacc[n][j] / lrow[j];
            o[obase + (size_t)row * EDIM + n * 16 + r16] = f2bf(ov);
        }
}

extern "C" void kernel_launch(void* const* d_in, const int* in_sizes, int n_in,
                              void* d_out, int out_size, void* d_ws, size_t ws_size,
                              hipStream_t stream) {
    const int*   idx     = (const int*)d_in[0];
    const float* tok_emb = (const float*)d_in[1];
    const float* pos_emb = (const float*)d_in[2];
    const float* Wq      = (const float*)d_in[3];
    const float* Wk      = (const float*)d_in[4];
    const float* Wv      = (const float*)d_in[5];
    const float* Wo      = (const float*)d_in[6];
    const float* bo      = (const float*)d_in[7];
    const float* ln1_s   = (const float*)d_in[8];
    const float* ln1_b   = (const float*)d_in[9];
    const float* W1      = (const float*)d_in[10];
    const float* b1      = (const float*)d_in[11];
    const float* W2      = (const float*)d_in[12];
    const float* b2      = (const float*)d_in[13];
    const float* ln2_s   = (const float*)d_in[14];
    const float* ln2_b   = (const float*)d_in[15];
    const float* lnf_s   = (const float*)d_in[16];
    const float* lnf_b   = (const float*)d_in[17];
    const float* lm_w    = (const float*)d_in[18];
    const float* lm_b    = (const float*)d_in[19];
    float* out = (float*)d_out;

    char* ws = (char*)d_ws;
    float*          x    = (float*)ws;                                  // 8 MB
    unsigned short* h    = (unsigned short*)(ws + (8  << 20));          // 4 MB
    unsigned short* qkv  = (unsigned short*)(ws + (12 << 20));          // 12 MB
    unsigned short* ao   = (unsigned short*)(ws + (24 << 20));          // 4 MB
    unsigned short* ff   = (unsigned short*)(ws + (28 << 20));          // 16 MB
    unsigned short* qkvT = (unsigned short*)(ws + (44 << 20));          // 6 MB [3072][1024]
    unsigned short* woT  = (unsigned short*)(ws + (50 << 20));          // 2 MB [1024][1024]
    unsigned short* w1T  = (unsigned short*)(ws + (52 << 20));          // 8 MB [4096][1024]
    unsigned short* w2T  = (unsigned short*)(ws + (60 << 20));          // 8 MB [1024][4096]
    unsigned short* lmT  = (unsigned short*)(ws + (68 << 20));          // 62.5 MB [32000][1024]
    float*          part = (float*)(ws + (68 << 20));                   // aliases lmT (<=32 MB)

    dim3 blk(256);
    embed_kernel<<<MROWS, blk, 0, stream>>>(idx, tok_emb, pos_emb, x);

    for (int l = 0; l < NLAYERS; ++l) {
        size_t eo = (size_t)l * EDIM * EDIM;
        wconv_layer_kernel<<<3072, blk, 0, stream>>>(
            Wq + eo, Wk + eo, Wv + eo, Wo + eo,
            W1 + (size_t)l * EDIM * FFDIM, W2 + (size_t)l * FFDIM * EDIM,
            qkvT, woT, w1T, w2T);

        ln_kernel<<<MROWS, blk, 0, stream>>>(x, ln1_s + l * EDIM, ln1_b + l * EDIM, h);
        // QKV: M2048 N3072 K1024, 16x12 tiles
        gemm_wide<0, 0><<<dim3(192, 1), blk, 0, stream>>>(h, qkvT, nullptr, nullptr, qkv, QKVN, EDIM, 16, 12, EDIM);
        attn_kernel<<<dim3(TSEQ / 64, NHEADS, NBATCH), blk, 0, stream>>>(qkv, ao);
        // Wo: N1024 K1024, 16x4 tiles, split-K 2
        gemm_wide<4, 0><<<dim3(64, 2), blk, 0, stream>>>(ao, woT, nullptr, part, nullptr, EDIM, EDIM, 16, 4, 512);
        reduce_kernel<2><<<MROWS, blk, 0, stream>>>(part, bo + l * EDIM, x);
        ln_kernel<<<MROWS, blk, 0, stream>>>(x, ln2_s + l * EDIM, ln2_b + l * EDIM, h);
        // FF1: N4096 K1024, 16x16 tiles
        gemm_wide<2, 0><<<dim3(256, 1), blk, 0, stream>>>(h, w1T, b1 + l * FFDIM, nullptr, ff, FFDIM, EDIM, 16, 16, EDIM);
        // FF2: N1024 K4096, 16x4 tiles, split-K 4
        gemm_wide<4, 0><<<dim3(64, 4), blk, 0, stream>>>(ff, w2T, nullptr, part, nullptr, EDIM, FFDIM, 16, 4, 1024);
        reduce_kernel<4><<<MROWS, blk, 0, stream>>>(part, b2 + l * EDIM, x);
    }
    ln_kernel<<<MROWS, blk, 0, stream>>>(x, lnf_s, lnf_b, h);
    wconv_kernel<<<dim3(16, 500), blk, 0, stream>>>(lm_w, lmT, EDIM, VOCAB);
    // lm head: N32000 K1024, 16x125 tiles, n-major for weight L2 residency
    gemm_wide<3, 1><<<dim3(2000, 1), blk, 0, stream>>>(h, lmT, lm_b, out, nullptr, VOCAB, EDIM, 16, 125, EDIM);
}

// Round 4
// 1554.532 us; speedup vs baseline: 2.3775x; 1.2815x over previous
//
#include <hip/hip_runtime.h>

#define EDIM 1024
#define NHEADS 16
#define HDIM 64
#define TSEQ 1024
#define NBATCH 2
#define MROWS 2048
#define FFDIM 4096
#define NLAYERS 8
#define VOCAB 32000
#define QKVN 3072

typedef __attribute__((ext_vector_type(4))) float f32x4;
typedef __attribute__((ext_vector_type(8))) short short8;

__device__ __forceinline__ unsigned short f2bf(float f) {
    union { float f; unsigned u; } v; v.f = f;
    unsigned r = v.u + 0x7fffu + ((v.u >> 16) & 1u);
    return (unsigned short)(r >> 16);
}

__device__ __forceinline__ f32x4 mfma_bf16(short8 a, short8 b, f32x4 c) {
    return __builtin_amdgcn_mfma_f32_16x16x32_bf16(a, b, c, 0, 0, 0);
}

// async global->LDS, 16B per lane; LDS dest = wave-uniform base + lane*16
__device__ __forceinline__ void gload16(const unsigned short* g, unsigned short* l) {
    __builtin_amdgcn_global_load_lds(
        (const __attribute__((address_space(1))) unsigned int*)g,
        (__attribute__((address_space(3))) unsigned int*)l, 16, 0, 0);
}

// ---------------- embedding ----------------
__global__ __launch_bounds__(256) void embed_kernel(
    const int* __restrict__ idx, const float* __restrict__ tok,
    const float* __restrict__ pos, float* __restrict__ x)
{
    int row = blockIdx.x;
    int t = row & (TSEQ - 1);
    int tokid = idx[row];
    const float* tp = tok + (size_t)tokid * EDIM;
    const float* pp = pos + (size_t)t * EDIM;
    float* xp = x + (size_t)row * EDIM;
    int c = threadIdx.x * 4;
    f32x4 a = *(const f32x4*)(tp + c);
    f32x4 b = *(const f32x4*)(pp + c);
    *(f32x4*)(xp + c) = a + b;
}

// ---------------- LN core (shared by ln_kernel / reduce_ln_kernel) ------------------
__device__ __forceinline__ void ln_store(
    f32x4 v, int tid, const float* __restrict__ sc, const float* __restrict__ bi,
    unsigned short* __restrict__ hrow)
{
    float sum = v[0] + v[1] + v[2] + v[3];
    float sq = v[0]*v[0] + v[1]*v[1] + v[2]*v[2] + v[3]*v[3];
    #pragma unroll
    for (int m = 1; m <= 32; m <<= 1) { sum += __shfl_xor(sum, m); sq += __shfl_xor(sq, m); }
    __shared__ float sh[8];
    int w = tid >> 6;
    if ((tid & 63) == 0) { sh[w] = sum; sh[4 + w] = sq; }
    __syncthreads();
    sum = sh[0] + sh[1] + sh[2] + sh[3];
    sq  = sh[4] + sh[5] + sh[6] + sh[7];
    float mu = sum * (1.0f / EDIM);
    float inv = rsqrtf(sq * (1.0f / EDIM) - mu * mu + 1e-5f);
    int c = tid * 4;
    unsigned o0 = (unsigned)f2bf((v[0] - mu) * inv * sc[c + 0] + bi[c + 0])
                | ((unsigned)f2bf((v[1] - mu) * inv * sc[c + 1] + bi[c + 1]) << 16);
    unsigned o1 = (unsigned)f2bf((v[2] - mu) * inv * sc[c + 2] + bi[c + 2])
                | ((unsigned)f2bf((v[3] - mu) * inv * sc[c + 3] + bi[c + 3]) << 16);
    unsigned* hp = (unsigned*)(hrow + c);
    hp[0] = o0; hp[1] = o1;
}

__global__ __launch_bounds__(256) void ln_kernel(
    const float* __restrict__ x, const float* __restrict__ sc,
    const float* __restrict__ bi, unsigned short* __restrict__ h)
{
    int row = blockIdx.x, tid = threadIdx.x;
    f32x4 v = *(const f32x4*)(x + (size_t)row * EDIM + tid * 4);
    ln_store(v, tid, sc, bi, h + (size_t)row * EDIM);
}

// fused: x += bias + sum_kz part;  h = LN(x)
template<int KZ>
__global__ __launch_bounds__(256) void reduce_ln_kernel(
    const float* __restrict__ part, const float* __restrict__ bias,
    float* __restrict__ x, const float* __restrict__ sc,
    const float* __restrict__ bi, unsigned short* __restrict__ h)
{
    int row = blockIdx.x, tid = threadIdx.x;
    int c = tid * 4;
    f32x4 s = *(const f32x4*)(x + (size_t)row * EDIM + c);
    s += *(const f32x4*)(bias + c);
    #pragma unroll
    for (int kz = 0; kz < KZ; ++kz)
        s += *(const f32x4*)(part + ((size_t)kz * MROWS + row) * EDIM + c);
    *(f32x4*)(x + (size_t)row * EDIM + c) = s;
    ln_store(s, tid, sc, bi, h + (size_t)row * EDIM);
}

// ---------------- weight convert+transpose tile (64x64) ----------------
__device__ __forceinline__ void conv_tile(
    const float* __restrict__ W, unsigned short* __restrict__ WT,
    int Kdim, int Ndim, int k0, int n0, int tid)
{
    __shared__ unsigned short T[64][72];
    int r = tid >> 4, c4 = (tid & 15) * 4;
    #pragma unroll
    for (int i = 0; i < 4; ++i) {
        f32x4 v = *(const f32x4*)(W + (size_t)(k0 + r + 16 * i) * Ndim + n0 + c4);
        T[c4 + 0][r + 16 * i] = f2bf(v[0]);
        T[c4 + 1][r + 16 * i] = f2bf(v[1]);
        T[c4 + 2][r + 16 * i] = f2bf(v[2]);
        T[c4 + 3][r + 16 * i] = f2bf(v[3]);
    }
    __syncthreads();
    int nr = tid >> 2, kc = (tid & 3) * 16;
    short8 o0 = *(const short8*)&T[nr][kc];
    short8 o1 = *(const short8*)&T[nr][kc + 8];
    *(short8*)(WT + (size_t)(n0 + nr) * Kdim + k0 + kc)     = o0;
    *(short8*)(WT + (size_t)(n0 + nr) * Kdim + k0 + kc + 8) = o1;
}

__global__ __launch_bounds__(256) void wconv_layer_kernel(
    const float* __restrict__ Wq, const float* __restrict__ Wk,
    const float* __restrict__ Wv, const float* __restrict__ Wo,
    const float* __restrict__ W1, const float* __restrict__ W2,
    unsigned short* __restrict__ qkvT, unsigned short* __restrict__ woT,
    unsigned short* __restrict__ w1T, unsigned short* __restrict__ w2T)
{
    int bid = blockIdx.x, tid = threadIdx.x;
    if (bid < 768) {
        int wsel = bid >> 8, t = bid & 255;
        const float* src = wsel == 0 ? Wq : (wsel == 1 ? Wk : Wv);
        conv_tile(src, qkvT + (size_t)wsel * EDIM * EDIM, EDIM, EDIM,
                  (t & 15) * 64, (t >> 4) * 64, tid);
    } else if (bid < 1024) {
        int t = bid - 768;
        conv_tile(Wo, woT, EDIM, EDIM, (t & 15) * 64, (t >> 4) * 64, tid);
    } else if (bid < 2048) {
        int t = bid - 1024;
        conv_tile(W1, w1T, EDIM, FFDIM, (t & 15) * 64, (t >> 4) * 64, tid);
    } else {
        int t = bid - 2048;
        conv_tile(W2, w2T, FFDIM, EDIM, (t >> 4) * 64, (t & 15) * 64, tid);
    }
}

__global__ __launch_bounds__(256) void wconv_kernel(
    const float* __restrict__ W, unsigned short* __restrict__ WT, int Kdim, int Ndim)
{
    conv_tile(W, WT, Kdim, Ndim, blockIdx.x * 64, blockIdx.y * 64, threadIdx.x);
}

// ---------------- narrow GEMM: block 128x128, 4 waves (2Mx2N), wave 64x64, BK=64 ---
// XOR-swizzled LDS (write: pre-swizzled global col; read: slot ^ (r16&7))
// EPI 0: ->bf16   2: +bias,gelu->bf16   4: partial f32 (split-K)
template<int EPI>
__global__ __launch_bounds__(256, 3) void gemm128(
    const unsigned short* __restrict__ A, const unsigned short* __restrict__ WT,
    const float* __restrict__ bias, float* __restrict__ Cf,
    unsigned short* __restrict__ Cb, int Ndim, int Kdim,
    int ntiles, int nwg, int kspan)
{
    __shared__ __align__(16) unsigned short A_lds[128][64];
    __shared__ __align__(16) unsigned short B_lds[128][64];
    int tid = threadIdx.x;
    int q8 = nwg >> 3;
    int swz = (int)(blockIdx.x & 7) * q8 + (int)(blockIdx.x >> 3);
    int bm0 = (swz / ntiles) * 128, bn0 = (swz % ntiles) * 128;
    int kz = blockIdx.y;
    int lane = tid & 63, w = tid >> 6;
    int wr = w >> 1, wc = w & 1;
    int r16 = lane & 15, cc = lane >> 4;
    int lrow = lane >> 3;
    int lcol = ((lane & 7) ^ lrow) * 8;     // pre-swizzled source column
    int sw = r16 & 7;                        // read-side XOR

    f32x4 acc[4][4];
    #pragma unroll
    for (int m = 0; m < 4; ++m)
        #pragma unroll
        for (int n = 0; n < 4; ++n) acc[m][n] = {0.f, 0.f, 0.f, 0.f};

    int kbeg = kz * kspan, kend = kbeg + kspan;
    for (int k0 = kbeg; k0 < kend; k0 += 64) {
        #pragma unroll
        for (int i = 0; i < 4; ++i) {
            int c = i * 4 + w;
            gload16(A + (size_t)(bm0 + c * 8 + lrow) * Kdim + k0 + lcol,
                    (unsigned short*)A_lds + c * 512);
            gload16(WT + (size_t)(bn0 + c * 8 + lrow) * Kdim + k0 + lcol,
                    (unsigned short*)B_lds + c * 512);
        }
        __syncthreads();
        #pragma unroll
        for (int kh = 0; kh < 2; ++kh) {
            short8 af[4], bfr[4];
            #pragma unroll
            for (int m = 0; m < 4; ++m)
                af[m] = *(const short8*)&A_lds[wr * 64 + m * 16 + r16][((kh * 4 + cc) ^ sw) * 8];
            #pragma unroll
            for (int n = 0; n < 4; ++n)
                bfr[n] = *(const short8*)&B_lds[wc * 64 + n * 16 + r16][((kh * 4 + cc) ^ sw) * 8];
            #pragma unroll
            for (int m = 0; m < 4; ++m)
                #pragma unroll
                for (int n = 0; n < 4; ++n)
                    acc[m][n] = mfma_bf16(af[m], bfr[n], acc[m][n]);
        }
        __syncthreads();
    }

    float* Cpart = Cf + (size_t)kz * MROWS * Ndim;
    #pragma unroll
    for (int m = 0; m < 4; ++m) {
        #pragma unroll
        for (int n = 0; n < 4; ++n) {
            #pragma unroll
            for (int j = 0; j < 4; ++j) {
                int row = bm0 + wr * 64 + m * 16 + cc * 4 + j;
                int col = bn0 + wc * 64 + n * 16 + r16;
                float vv = acc[m][n][j];
                if constexpr (EPI == 2) {
                    vv += bias[col];
                    vv = 0.5f * vv * (1.0f + erff(vv * 0.70710678118654752f));
                }
                if constexpr (EPI == 0 || EPI == 2)
                    Cb[(size_t)row * Ndim + col] = f2bf(vv);
                else
                    Cpart[(size_t)row * Ndim + col] = vv;
            }
        }
    }
}

// ---------------- wide GEMM (lm head): block 128Mx256N, wave 64x128, n-major -------
__global__ __launch_bounds__(256, 2) void gemm_wide_lm(
    const unsigned short* __restrict__ A, const unsigned short* __restrict__ WT,
    const float* __restrict__ bias, float* __restrict__ Cf,
    int Ndim, int Kdim, int mtiles, int ntiles)
{
    __shared__ __align__(16) unsigned short A_lds[128][64];
    __shared__ __align__(16) unsigned short B_lds[256][64];
    int tid = threadIdx.x;
    int nwg = mtiles * ntiles;
    int q8 = nwg >> 3;
    int swz = (int)(blockIdx.x & 7) * q8 + (int)(blockIdx.x >> 3);
    int bn0 = (swz / mtiles) * 256, bm0 = (swz % mtiles) * 128;
    int lane = tid & 63, w = tid >> 6;
    int wr = w >> 1, wc = w & 1;
    int r16 = lane & 15, cc = lane >> 4;
    int lrow = lane >> 3;
    int lcol = ((lane & 7) ^ lrow) * 8;
    int sw = r16 & 7;

    f32x4 acc[4][8];
    #pragma unroll
    for (int m = 0; m < 4; ++m)
        #pragma unroll
        for (int n = 0; n < 8; ++n) acc[m][n] = {0.f, 0.f, 0.f, 0.f};

    for (int k0 = 0; k0 < Kdim; k0 += 64) {
        #pragma unroll
        for (int i = 0; i < 4; ++i) {
            int c = i * 4 + w;
            gload16(A + (size_t)(bm0 + c * 8 + lrow) * Kdim + k0 + lcol,
                    (unsigned short*)A_lds + c * 512);
        }
        #pragma unroll
        for (int i = 0; i < 8; ++i) {
            int c = i * 4 + w;
            gload16(WT + (size_t)(bn0 + c * 8 + lrow) * Kdim + k0 + lcol,
                    (unsigned short*)B_lds + c * 512);
        }
        __syncthreads();
        #pragma unroll
        for (int kh = 0; kh < 2; ++kh) {
            short8 af[4], bfr[8];
            #pragma unroll
            for (int m = 0; m < 4; ++m)
                af[m] = *(const short8*)&A_lds[wr * 64 + m * 16 + r16][((kh * 4 + cc) ^ sw) * 8];
            #pragma unroll
            for (int n = 0; n < 8; ++n)
                bfr[n] = *(const short8*)&B_lds[wc * 128 + n * 16 + r16][((kh * 4 + cc) ^ sw) * 8];
            #pragma unroll
            for (int m = 0; m < 4; ++m)
                #pragma unroll
                for (int n = 0; n < 8; ++n)
                    acc[m][n] = mfma_bf16(af[m], bfr[n], acc[m][n]);
        }
        __syncthreads();
    }

    #pragma unroll
    for (int m = 0; m < 4; ++m) {
        #pragma unroll
        for (int n = 0; n < 8; ++n) {
            #pragma unroll
            for (int j = 0; j < 4; ++j) {
                int row = bm0 + wr * 64 + m * 16 + cc * 4 + j;
                int col = bn0 + wc * 128 + n * 16 + r16;
                Cf[(size_t)row * Ndim + col] = acc[m][n][j] + bias[col];
            }
        }
    }
}

// ---------------- flash attention (q,k,v from fused qkv buffer, stride QKVN) -------
__global__ __launch_bounds__(256) void attn_kernel(
    const unsigned short* __restrict__ qkv, unsigned short* __restrict__ o)
{
    __shared__ __align__(16) unsigned short K_lds[64][72];
    __shared__ __align__(16) unsigned short VT_lds[64][72];
    __shared__ __align__(16) unsigned short P_lds[4][16][72];

    int qt = blockIdx.x, head = blockIdx.y, bb = blockIdx.z;
    int tid = threadIdx.x, w = tid >> 6, lane = tid & 63;
    int r16 = lane & 15, cc = lane >> 4;
    size_t base = ((size_t)bb * TSEQ) * QKVN + head * HDIM;
    const unsigned short* q = qkv + base;
    const unsigned short* k = qkv + base + EDIM;
    const unsigned short* v = qkv + base + 2 * EDIM;
    size_t obase = ((size_t)bb * TSEQ) * EDIM + head * HDIM;
    int qbase = qt * 64;

    const unsigned short* qp = q + (size_t)(qbase + w * 16 + r16) * QKVN;
    short8 aq0 = *(const short8*)(qp + cc * 8);
    short8 aq1 = *(const short8*)(qp + 32 + cc * 8);

    f32x4 oacc[4];
    float mrow[4], lrow[4];
    #pragma unroll
    for (int n = 0; n < 4; ++n) oacc[n] = {0.f, 0.f, 0.f, 0.f};
    #pragma unroll
    for (int j = 0; j < 4; ++j) { mrow[j] = -1e30f; lrow[j] = 0.f; }

    int krow = tid >> 2, kch = tid & 3;
    int vkey2 = (tid & 31) * 2, vdh = tid >> 5;   // 2 keys x 8 d per thread

    for (int kt = 0; kt <= qt; ++kt) {
        int kbase = kt * 64;
        const unsigned short* kp = k + (size_t)(kbase + krow) * QKVN + kch * 16;
        short8 kv0 = *(const short8*)kp;
        short8 kv1 = *(const short8*)(kp + 8);
        *(short8*)&K_lds[krow][kch * 16]     = kv0;
        *(short8*)&K_lds[krow][kch * 16 + 8] = kv1;
        // V transposed: packed 2-key u32 writes
        const unsigned short* vp0 = v + (size_t)(kbase + vkey2) * QKVN + vdh * 8;
        short8 v0 = *(const short8*)vp0;
        short8 v1 = *(const short8*)(vp0 + QKVN);
        #pragma unroll
        for (int i = 0; i < 8; ++i) {
            unsigned pk = (unsigned)(unsigned short)v0[i]
                        | ((unsigned)(unsigned short)v1[i] << 16);
            *(unsigned*)&VT_lds[vdh * 8 + i][vkey2] = pk;
        }
        __syncthreads();

        f32x4 s[4];
        #pragma unroll
        for (int n = 0; n < 4; ++n) {
            short8 bk0 = *(const short8*)&K_lds[n * 16 + r16][cc * 8];
            short8 bk1 = *(const short8*)&K_lds[n * 16 + r16][32 + cc * 8];
            f32x4 z = {0.f, 0.f, 0.f, 0.f};
            z = mfma_bf16(aq0, bk0, z);
            z = mfma_bf16(aq1, bk1, z);
            s[n] = z;
        }
        bool diag = (kt == qt);
        float p[4][4];
        #pragma unroll
        for (int n = 0; n < 4; ++n)
            #pragma unroll
            for (int j = 0; j < 4; ++j) {
                float sv = s[n][j] * 0.125f;
                if (diag && (kbase + n * 16 + r16 > qbase + w * 16 + cc * 4 + j)) sv = -1e30f;
                p[n][j] = sv;
            }
        float alpha[4];
        #pragma unroll
        for (int j = 0; j < 4; ++j) {
            float tmax = fmaxf(fmaxf(p[0][j], p[1][j]), fmaxf(p[2][j], p[3][j]));
            #pragma unroll
            for (int mm = 1; mm <= 8; mm <<= 1) tmax = fmaxf(tmax, __shfl_xor(tmax, mm));
            float mnew = fmaxf(mrow[j], tmax);
            alpha[j] = __expf(mrow[j] - mnew);
            mrow[j] = mnew;
            float tsum = 0.f;
            #pragma unroll
            for (int n = 0; n < 4; ++n) {
                float pe = __expf(p[n][j] - mnew);
                p[n][j] = pe;
                tsum += pe;
            }
            #pragma unroll
            for (int mm = 1; mm <= 8; mm <<= 1) tsum += __shfl_xor(tsum, mm);
            lrow[j] = lrow[j] * alpha[j] + tsum;
        }
        #pragma unroll
        for (int n = 0; n < 4; ++n) {
            #pragma unroll
            for (int j = 0; j < 4; ++j) {
                P_lds[w][cc * 4 + j][n * 16 + r16] = f2bf(p[n][j]);
                oacc[n][j] *= alpha[j];
            }
        }
        short8 pa0 = *(const short8*)&P_lds[w][r16][cc * 8];
        short8 pa1 = *(const short8*)&P_lds[w][r16][32 + cc * 8];
        #pragma unroll
        for (int n = 0; n < 4; ++n) {
            short8 bv0 = *(const short8*)&VT_lds[n * 16 + r16][cc * 8];
            short8 bv1 = *(const short8*)&VT_lds[n * 16 + r16][32 + cc * 8];
            oacc[n] = mfma_bf16(pa0, bv0, oacc[n]);
            oacc[n] = mfma_bf16(pa1, bv1, oacc[n]);
        }
        __syncthreads();
    }
    float rl[4];
    #pragma unroll
    for (int j = 0; j < 4; ++j) rl[j] = 1.0f / lrow[j];
    #pragma unroll
    for (int n = 0; n < 4; ++n)
        #pragma unroll
        for (int j = 0; j < 4; ++j) {
            int row = qbase + w * 16 + cc * 4 + j;
            o[obase + (size_t)row * EDIM + n * 16 + r16] = f2bf(oacc[n][j] * rl[j]);
        }
}

extern "C" void kernel_launch(void* const* d_in, const int* in_sizes, int n_in,
                              void* d_out, int out_size, void* d_ws, size_t ws_size,
                              hipStream_t stream) {
    const int*   idx     = (const int*)d_in[0];
    const float* tok_emb = (const float*)d_in[1];
    const float* pos_emb = (const float*)d_in[2];
    const float* Wq      = (const float*)d_in[3];
    const float* Wk      = (const float*)d_in[4];
    const float* Wv      = (const float*)d_in[5];
    const float* Wo      = (const float*)d_in[6];
    const float* bo      = (const float*)d_in[7];
    const float* ln1_s   = (const float*)d_in[8];
    const float* ln1_b   = (const float*)d_in[9];
    const float* W1      = (const float*)d_in[10];
    const float* b1      = (const float*)d_in[11];
    const float* W2      = (const float*)d_in[12];
    const float* b2      = (const float*)d_in[13];
    const float* ln2_s   = (const float*)d_in[14];
    const float* ln2_b   = (const float*)d_in[15];
    const float* lnf_s   = (const float*)d_in[16];
    const float* lnf_b   = (const float*)d_in[17];
    const float* lm_w    = (const float*)d_in[18];
    const float* lm_b    = (const float*)d_in[19];
    float* out = (float*)d_out;

    char* ws = (char*)d_ws;
    float*          x    = (float*)ws;                                  // 8 MB
    unsigned short* h    = (unsigned short*)(ws + (8  << 20));          // 4 MB
    unsigned short* qkv  = (unsigned short*)(ws + (12 << 20));          // 12 MB
    unsigned short* ao   = (unsigned short*)(ws + (24 << 20));          // 4 MB
    unsigned short* ff   = (unsigned short*)(ws + (28 << 20));          // 16 MB
    unsigned short* qkvT = (unsigned short*)(ws + (44 << 20));          // 6 MB [3072][1024]
    unsigned short* woT  = (unsigned short*)(ws + (50 << 20));          // 2 MB [1024][1024]
    unsigned short* w1T  = (unsigned short*)(ws + (52 << 20));          // 8 MB [4096][1024]
    unsigned short* w2T  = (unsigned short*)(ws + (60 << 20));          // 8 MB [1024][4096]
    unsigned short* lmT  = (unsigned short*)(ws + (68 << 20));          // 62.5 MB [32000][1024]
    float*          part = (float*)(ws + (68 << 20));                   // aliases lmT (32 MB)

    dim3 blk(256);
    embed_kernel<<<MROWS, blk, 0, stream>>>(idx, tok_emb, pos_emb, x);
    ln_kernel<<<MROWS, blk, 0, stream>>>(x, ln1_s, ln1_b, h);

    for (int l = 0; l < NLAYERS; ++l) {
        size_t eo = (size_t)l * EDIM * EDIM;
        wconv_layer_kernel<<<3072, blk, 0, stream>>>(
            Wq + eo, Wk + eo, Wv + eo, Wo + eo,
            W1 + (size_t)l * EDIM * FFDIM, W2 + (size_t)l * FFDIM * EDIM,
            qkvT, woT, w1T, w2T);

        // QKV: M2048 N3072 K1024 -> 16x24 = 384 wg
        gemm128<0><<<dim3(384, 1), blk, 0, stream>>>(h, qkvT, nullptr, nullptr, qkv, QKVN, EDIM, 24, 384, EDIM);
        attn_kernel<<<dim3(TSEQ / 64, NHEADS, NBATCH), blk, 0, stream>>>(qkv, ao);
        // Wo: N1024 K1024, 16x8 = 128 wg x kz4 (kspan 256)
        gemm128<4><<<dim3(128, 4), blk, 0, stream>>>(ao, woT, nullptr, part, nullptr, EDIM, EDIM, 8, 128, 256);
        reduce_ln_kernel<4><<<MROWS, blk, 0, stream>>>(part, bo + l * EDIM, x, ln2_s + l * EDIM, ln2_b + l * EDIM, h);
        // FF1: N4096 K1024 -> 16x32 = 512 wg
        gemm128<2><<<dim3(512, 1), blk, 0, stream>>>(h, w1T, b1 + l * FFDIM, nullptr, ff, FFDIM, EDIM, 32, 512, EDIM);
        // FF2: N1024 K4096, 16x8 = 128 wg x kz4 (kspan 1024)
        gemm128<4><<<dim3(128, 4), blk, 0, stream>>>(ff, w2T, nullptr, part, nullptr, EDIM, FFDIM, 8, 128, 1024);
        if (l < NLAYERS - 1)
            reduce_ln_kernel<4><<<MROWS, blk, 0, stream>>>(part, b2 + l * EDIM, x, ln1_s + (l + 1) * EDIM, ln1_b + (l + 1) * EDIM, h);
        else
            reduce_ln_kernel<4><<<MROWS, blk, 0, stream>>>(part, b2 + l * EDIM, x, lnf_s, lnf_b, h);
    }
    wconv_kernel<<<dim3(16, 500), blk, 0, stream>>>(lm_w, lmT, EDIM, VOCAB);
    // lm head: N32000 K1024, 16m x 125n (n-major) = 2000 wg
    gemm_wide_lm<<<dim3(2000, 1), blk, 0, stream>>>(h, lmT, lm_b, out, VOCAB, EDIM, 16, 125);
}